// Round 1
// baseline (259.467 us; speedup 1.0000x reference)
//
#include <hip/hip_runtime.h>
#include <hip/hip_bf16.h>
#include <math.h>

#define S 1024
#define D 1024
#define P 2816
#define R 64
#define E 8
#define M 16
#define KSPLIT 4
#define KQ (P / KSPLIT)   // 704
#define NIT (KQ / 64)     // 11
#define ZT 16             // k_t K-split; K-slice = D/ZT = 64
#define ACH ((E * P * R) / 8)  // 180224 adapter short8-chunks

typedef __attribute__((ext_vector_type(8))) short short8;   // 8 bf16 (4 VGPRs)
typedef __attribute__((ext_vector_type(4))) float floatx4;  // MFMA acc

static __device__ inline unsigned short f2bf(float f) {
  __hip_bfloat16 h = __float2bfloat16(f);
  return *reinterpret_cast<unsigned short*>(&h);
}
static __device__ inline short8 pack8(float4 a, float4 b) {
  short8 v;
  v[0] = f2bf(a.x); v[1] = f2bf(a.y); v[2] = f2bf(a.z); v[3] = f2bf(a.w);
  v[4] = f2bf(b.x); v[5] = f2bf(b.y); v[6] = f2bf(b.z); v[7] = f2bf(b.w);
  return v;
}

// ---------------------------------------------------------------------------
// K1 (fused pre-pass), grid 256 x 256:
//  - zero out (4 MB) + tbuf (0.5 MB)
//  - counting sort (block 0)
//  - softmax alphas + mixed bases, written TRANSPOSED: mxT[e][n=r|64+r][d] bf16
//  - H -> bf16 copy (Hbf), adapters -> bf16 (Aubf/Agbf)
// ---------------------------------------------------------------------------
__global__ __launch_bounds__(256) void k_pre(
    const float* __restrict__ up_logits, const float* __restrict__ gate_logits,
    const float* __restrict__ up_bank, const float* __restrict__ gate_bank,
    const float* __restrict__ H, const float* __restrict__ Aup,
    const float* __restrict__ Agate, const int* __restrict__ idx,
    unsigned short* __restrict__ Hbf, unsigned short* __restrict__ mxT,
    unsigned short* __restrict__ Aubf, unsigned short* __restrict__ Agbf,
    int* __restrict__ perm, int* __restrict__ offs,
    float* __restrict__ tbuf, float* __restrict__ out) {
  int b = blockIdx.x, t = threadIdx.x;
  int g = b * 256 + t;
  // zero the output (k_down accumulates with atomics)
  float4 z4 = make_float4(0.f, 0.f, 0.f, 0.f);
#pragma unroll
  for (int j = 0; j < 4; ++j)
    *(float4*)(out + (size_t)b * 4096 + j * 1024 + t * 4) = z4;
  // zero tbuf (k_t accumulates with atomics): S*128 floats, 2/thread
  *(float2*)(tbuf + (size_t)g * 2) = make_float2(0.f, 0.f);

  if (b == 0) {  // counting sort, 4 tokens/thread
    __shared__ int hist[E];
    __shared__ int basearr[E];
    if (t < E) hist[t] = 0;
    __syncthreads();
    int e4[4];
#pragma unroll
    for (int j = 0; j < 4; ++j) {
      e4[j] = idx[t + j * 256];
      atomicAdd(&hist[e4[j]], 1);
    }
    __syncthreads();
    if (t == 0) {
      int run = 0;
      for (int i = 0; i < E; ++i) { basearr[i] = run; offs[i] = run; run += hist[i]; }
      offs[E] = S;
    }
    __syncthreads();
#pragma unroll
    for (int j = 0; j < 4; ++j) {
      int pos = atomicAdd(&basearr[e4[j]], 1);
      perm[pos] = t + j * 256;
    }
  }

  // H -> bf16, 16 elems/thread (coalesced)
  {
    const float* hs = H + (size_t)g * 16;
    float4 h0 = *(const float4*)hs, h1 = *(const float4*)(hs + 4);
    float4 h2 = *(const float4*)(hs + 8), h3 = *(const float4*)(hs + 12);
    *(short8*)(Hbf + (size_t)g * 16) = pack8(h0, h1);
    *(short8*)(Hbf + (size_t)g * 16 + 8) = pack8(h2, h3);
  }
  // adapters -> bf16 (grid-stride over short8 chunks)
#pragma unroll
  for (int j = 0; j < 3; ++j) {
    int c = g + j * 65536;
    if (c < ACH) {
      const float* su = Aup + (size_t)c * 8;
      const float* sg = Agate + (size_t)c * 8;
      float4 u0 = *(const float4*)su, u1 = *(const float4*)(su + 4);
      float4 g0 = *(const float4*)sg, g1 = *(const float4*)(sg + 4);
      *(short8*)(Aubf + (size_t)c * 8) = pack8(u0, u1);
      *(short8*)(Agbf + (size_t)c * 8) = pack8(g0, g1);
    }
  }

  __shared__ float alpha[2][E][M];
  if (t < 16) {
    int mat = t >> 3, e = t & 7;
    const float* lg = (mat ? gate_logits : up_logits) + e * M;
    float v[M], mx = -1e30f, s = 0.f;
#pragma unroll
    for (int m = 0; m < M; ++m) { v[m] = lg[m]; mx = fmaxf(mx, v[m]); }
#pragma unroll
    for (int m = 0; m < M; ++m) { v[m] = expf(v[m] - mx); s += v[m]; }
#pragma unroll
    for (int m = 0; m < M; ++m) alpha[mat][e][m] = v[m] / s;
  }
  __syncthreads();
  int d = g >> 6, r = g & 63;
  float au[E] = {0, 0, 0, 0, 0, 0, 0, 0}, ag[E] = {0, 0, 0, 0, 0, 0, 0, 0};
#pragma unroll
  for (int m = 0; m < M; ++m) {
    float vu = up_bank[((size_t)m * D + d) * R + r];
    float vg = gate_bank[((size_t)m * D + d) * R + r];
#pragma unroll
    for (int e = 0; e < E; ++e) {
      au[e] += alpha[0][e][m] * vu;
      ag[e] += alpha[1][e][m] * vg;
    }
  }
  // transposed store: row n (r for up, 64+r for gate), col d. Ready for k_t's
  // B-fragment short8 loads (scattered 2B stores, 4 MB total -- cheap).
#pragma unroll
  for (int e = 0; e < E; ++e) {
    mxT[((size_t)e * 128 + r) * D + d] = f2bf(au[e]);
    mxT[((size_t)e * 128 + 64 + r) * D + d] = f2bf(ag[e]);
  }
}

// ---------------------------------------------------------------------------
// K2: t[pos, n] = H[tok, :] @ mixed^T  (n = 0..63 up, 64..127 gate)
// No LDS, no barriers: fragments straight from L2 (Hbf gather + mxT rows).
// grid (E, 4 tok-tiles of 64, ZT=16 K-slices of 64), block 256 = 4 indep waves,
// wave = 16 tok x 128 n. Accumulate K-slices into f32 tbuf via atomics
// (replaces the old tpart + k_tred reduction kernel).
// gridDim.x == 8 -> expert-e blocks pinned to XCD e.
// ---------------------------------------------------------------------------
__global__ __launch_bounds__(256) void k_t(
    const unsigned short* __restrict__ Hbf, const unsigned short* __restrict__ mxT,
    const int* __restrict__ perm, const int* __restrict__ offs,
    float* __restrict__ tbuf) {
  int e = blockIdx.x;
  int end = offs[e + 1];
  int t = threadIdx.x, lane = t & 63, w = t >> 6;
  int quad = lane >> 4, l15 = lane & 15;
  int row0 = offs[e] + blockIdx.y * 64 + w * 16;
  if (row0 >= end) return;  // wave-uniform, no barriers below
  int k0 = blockIdx.z * (D / ZT);
  int pos = row0 + l15;
  int tok = (pos < end) ? perm[pos] : -1;
  const unsigned short* hrow = Hbf + (size_t)(tok < 0 ? 0 : tok) * D + k0;
  floatx4 acc[8];
#pragma unroll
  for (int nt = 0; nt < 8; ++nt) acc[nt] = (floatx4){0.f, 0.f, 0.f, 0.f};
#pragma unroll
  for (int ks = 0; ks < 2; ++ks) {
    int kc = ks * 32 + quad * 8;
    short8 a = (short8){0, 0, 0, 0, 0, 0, 0, 0};
    if (tok >= 0) a = *(const short8*)(hrow + kc);
#pragma unroll
    for (int nt = 0; nt < 8; ++nt) {
      short8 bb = *(const short8*)(mxT + ((size_t)e * 128 + nt * 16 + l15) * D + k0 + kc);
      acc[nt] = __builtin_amdgcn_mfma_f32_16x16x32_bf16(a, bb, acc[nt], 0, 0, 0);
    }
  }
#pragma unroll
  for (int reg = 0; reg < 4; ++reg) {
    int p = row0 + quad * 4 + reg;
    if (p < end) {
#pragma unroll
      for (int nt = 0; nt < 8; ++nt)
        atomicAdd(&tbuf[(size_t)p * 128 + nt * 16 + l15], acc[nt][reg]);
    }
  }
}

// ---------------------------------------------------------------------------
// K3: inter[pos, p] = silu(t_g @ Ag[p]) * (t_u @ Au[p]), bf16 out.
// No LDS, no barriers. grid (E, 16 tok-tiles of 16, P/256=11), block 256 =
// 4 indep waves, wave = 16 tok x 64 p. a-frags: tbuf f32 -> bf16 in-register;
// b-frags: pre-converted bf16 adapters (contiguous short8 rows, L2-resident).
// ---------------------------------------------------------------------------
__global__ __launch_bounds__(256) void k_inter(
    const float* __restrict__ tbuf, const unsigned short* __restrict__ Aubf,
    const unsigned short* __restrict__ Agbf, const int* __restrict__ offs,
    unsigned short* __restrict__ inter) {
  int e = blockIdx.x;
  int start = offs[e] + blockIdx.y * 16;
  int end = offs[e + 1];
  if (start >= end) return;
  int t = threadIdx.x, lane = t & 63, w = t >> 6;
  int quad = lane >> 4, l15 = lane & 15;
  int p0 = blockIdx.z * 256 + w * 64;
  int pos = start + l15;
  bool okA = pos < end;
  floatx4 accu[4], accg[4];
#pragma unroll
  for (int nt = 0; nt < 4; ++nt) {
    accu[nt] = (floatx4){0.f, 0.f, 0.f, 0.f};
    accg[nt] = (floatx4){0.f, 0.f, 0.f, 0.f};
  }
#pragma unroll
  for (int ks = 0; ks < 2; ++ks) {
    int kc = ks * 32 + quad * 8;
    short8 au = (short8){0, 0, 0, 0, 0, 0, 0, 0};
    short8 ag = (short8){0, 0, 0, 0, 0, 0, 0, 0};
    if (okA) {
      const float* tp = tbuf + (size_t)pos * 128 + kc;
      au = pack8(*(const float4*)tp, *(const float4*)(tp + 4));
      ag = pack8(*(const float4*)(tp + 64), *(const float4*)(tp + 68));
    }
#pragma unroll
    for (int nt = 0; nt < 4; ++nt) {
      size_t prow = (size_t)e * P + p0 + nt * 16 + l15;
      short8 bu = *(const short8*)(Aubf + prow * R + kc);
      short8 bg = *(const short8*)(Agbf + prow * R + kc);
      accu[nt] = __builtin_amdgcn_mfma_f32_16x16x32_bf16(au, bu, accu[nt], 0, 0, 0);
      accg[nt] = __builtin_amdgcn_mfma_f32_16x16x32_bf16(ag, bg, accg[nt], 0, 0, 0);
    }
  }
#pragma unroll
  for (int nt = 0; nt < 4; ++nt)
#pragma unroll
    for (int reg = 0; reg < 4; ++reg) {
      int prow = start + quad * 4 + reg;
      if (prow < end) {
        float gv = accg[nt][reg], uv = accu[nt][reg];
        float val = uv * (gv / (1.f + __expf(-gv)));
        inter[(size_t)prow * P + p0 + nt * 16 + l15] = f2bf(val);
      }
    }
}

// ---------------------------------------------------------------------------
// K4: out[tok, d] += wts[tok] * (inter @ Wd^T). Register-prefetched LDS loop
// (Wd must be staged: reused by 4 waves / 64 tokens). 64-tok y-tiles to match
// the ~128 tok/expert population: grid (E, 4, 64) -> ~1100 active blocks
// (~4.3/CU) vs old 512 (2/CU); LDS 18.4 KB (was 46 KB).
// z: kz = bz>>4 (K-quarter of 704), d0 = (bz&15)*64. Expert-e -> XCD e; the
// ~2 active y-tiles sharing a Wd slice are dispatched 8 blocks apart -> L2 hit.
// ---------------------------------------------------------------------------
__global__ __launch_bounds__(256) void k_down(
    const unsigned short* __restrict__ inter, const float* __restrict__ Wd,
    const int* __restrict__ perm, const int* __restrict__ offs,
    const float* __restrict__ wts, float* __restrict__ out) {
  int e = blockIdx.x;
  int start = offs[e] + blockIdx.y * 64;
  int end = offs[e + 1];
  if (start >= end) return;
  int kz = blockIdx.z >> 4;
  int d0 = (blockIdx.z & 15) * 64;
  __shared__ unsigned short As[64][72];  // 9.2 KB
  __shared__ unsigned short Bs[64][72];  // 9.2 KB
  int t = threadIdx.x;
  int lane = t & 63, w = t >> 6, quad = lane >> 4, l15 = lane & 15;

  // A staging: row t>>2 (64 rows), 32B/thread. B staging: row t>>2, 64B/thread.
  int arow = t >> 2;
  int apos = start + arow;
  bool aok = apos < end;
  const unsigned short* aptr =
      inter + (size_t)(aok ? apos : start) * P + kz * KQ + (t & 3) * 16;
  const float* bptr = Wd + ((size_t)(e * D + d0 + (t >> 2)) * P + kz * KQ + (t & 3) * 16);

  short8 pa0 = (short8){0, 0, 0, 0, 0, 0, 0, 0}, pa1 = pa0;
  float4 pb[4];
  if (aok) { pa0 = *(const short8*)aptr; pa1 = *(const short8*)(aptr + 8); }
#pragma unroll
  for (int q = 0; q < 4; ++q) pb[q] = *(const float4*)(bptr + q * 4);

  floatx4 acc[4];
#pragma unroll
  for (int dt = 0; dt < 4; ++dt) acc[dt] = (floatx4){0.f, 0.f, 0.f, 0.f};

  for (int it = 0; it < NIT; ++it) {
    *(short8*)&As[arow][(t & 3) * 16] = pa0;
    *(short8*)&As[arow][(t & 3) * 16 + 8] = pa1;
    *(short8*)&Bs[t >> 2][(t & 3) * 16] = pack8(pb[0], pb[1]);
    *(short8*)&Bs[t >> 2][(t & 3) * 16 + 8] = pack8(pb[2], pb[3]);
    __syncthreads();
    if (it + 1 < NIT) {  // prefetch next tile (overlaps MFMA below)
      int k0 = (it + 1) * 64;
      if (aok) { pa0 = *(const short8*)(aptr + k0); pa1 = *(const short8*)(aptr + k0 + 8); }
#pragma unroll
      for (int q = 0; q < 4; ++q) pb[q] = *(const float4*)(bptr + k0 + q * 4);
    }
#pragma unroll
    for (int ks = 0; ks < 2; ++ks) {
      int kc = ks * 32 + quad * 8;
      short8 a = *(const short8*)&As[w * 16 + l15][kc];
#pragma unroll
      for (int dt = 0; dt < 4; ++dt) {
        short8 b = *(const short8*)&Bs[dt * 16 + l15][kc];
        acc[dt] = __builtin_amdgcn_mfma_f32_16x16x32_bf16(a, b, acc[dt], 0, 0, 0);
      }
    }
    __syncthreads();
  }
#pragma unroll
  for (int reg = 0; reg < 4; ++reg) {
    int pos = start + w * 16 + quad * 4 + reg;
    if (pos < end) {
      int tok = perm[pos];
      float wt = wts[tok];
#pragma unroll
      for (int dt = 0; dt < 4; ++dt)
        atomicAdd(&out[(size_t)tok * D + d0 + dt * 16 + l15], acc[dt][reg] * wt);
    }
  }
}

// ---------------------------------------------------------------------------
extern "C" void kernel_launch(void* const* d_in, const int* in_sizes, int n_in,
                              void* d_out, int out_size, void* d_ws, size_t ws_size,
                              hipStream_t stream) {
  const float* H = (const float*)d_in[0];
  const int* idx = (const int*)d_in[1];
  const float* wts = (const float*)d_in[2];
  const float* Aup = (const float*)d_in[3];
  const float* Agate = (const float*)d_in[4];
  const float* upl = (const float*)d_in[5];
  const float* gatel = (const float*)d_in[6];
  const float* Wd = (const float*)d_in[7];
  const float* upb = (const float*)d_in[8];
  const float* gateb = (const float*)d_in[9];
  float* out = (float*)d_out;

  char* ws = (char*)d_ws;
  unsigned short* Hbf = (unsigned short*)ws;                  // S*D bf16 = 2 MB
  unsigned short* mxT = Hbf + (size_t)S * D;                  // E*128*D bf16 = 2 MB
  unsigned short* Aubf = mxT + (size_t)E * 128 * D;           // E*P*R bf16 = 2.9 MB
  unsigned short* Agbf = Aubf + (size_t)E * P * R;            // 2.9 MB
  unsigned short* inter = Agbf + (size_t)E * P * R;           // S*P bf16 = 5.8 MB
  float* tbuf = (float*)(inter + (size_t)S * P);              // S*128 f32 = 0.5 MB
  int* perm = (int*)(tbuf + (size_t)S * 128);
  int* offs = perm + S;

  k_pre<<<256, 256, 0, stream>>>(upl, gatel, upb, gateb, H, Aup, Agate, idx,
                                 Hbf, mxT, Aubf, Agbf, perm, offs, tbuf, out);
  k_t<<<dim3(E, 4, ZT), 256, 0, stream>>>(Hbf, mxT, perm, offs, tbuf);
  k_inter<<<dim3(E, 16, P / 256), 256, 0, stream>>>(tbuf, Aubf, Agbf, offs, inter);
  k_down<<<dim3(E, 4, KSPLIT * 16), 256, 0, stream>>>(inter, Wd, perm, offs, wts, out);
}